// Round 5
// baseline (456.597 us; speedup 1.0000x reference)
//
#include <hip/hip_runtime.h>
#include <stdint.h>

#define M_DIM 8192
#define K_DIM 4096
#define O_DIM 4096
#define NWORDS 128

typedef __attribute__((ext_vector_type(8))) short bf16x8;
typedef __attribute__((ext_vector_type(16))) float f32x16;
typedef __attribute__((ext_vector_type(4))) float fvec4;
typedef __attribute__((ext_vector_type(4))) unsigned uvec4;

__device__ __forceinline__ unsigned f32_to_bf16u(float f) {
  union { float f; unsigned u; } v; v.f = f;
  return (v.u + 0x7FFFu + ((v.u >> 16) & 1u)) >> 16;   // round-to-nearest-even
}

__device__ __forceinline__ unsigned pack_bf16x2(float lo, float hi) {
  return f32_to_bf16u(lo) | (f32_to_bf16u(hi) << 16);
}

// ---- phase 1: x fp32->bf16 AND ternary unpack (unchanged from R4) -----------
__global__ __launch_bounds__(256) void prep_kernel(const fvec4* __restrict__ x,
                                                   uvec4* __restrict__ xb4,
                                                   const unsigned* __restrict__ nz,
                                                   const unsigned* __restrict__ sgn,
                                                   unsigned short* __restrict__ wb) {
  const int b   = blockIdx.x;
  const int tid = threadIdx.x;
  if (b < 2048) {
    for (long p = (long)b * 256 + tid; p < 4194304; p += 524288) {
      const fvec4 v0 = x[2 * p];
      const fvec4 v1 = x[2 * p + 1];
      uvec4 o;
      o.x = pack_bf16x2(v0.x, v0.y);
      o.y = pack_bf16x2(v0.z, v0.w);
      o.z = pack_bf16x2(v1.x, v1.y);
      o.w = pack_bf16x2(v1.z, v1.w);
      xb4[p] = o;
    }
  } else {
    for (long i = (long)(b - 2048) * 256 + tid; i < 2097152; i += 131072) {
      const int w = (int)(i >> 2);
      const int q = (int)(i & 3);
      const unsigned n = nz[w] >> (8 * q);
      const unsigned s = sgn[w] >> (8 * q);
      unsigned out[4];
#pragma unroll
      for (int pq = 0; pq < 4; ++pq) {
        const int j0 = 2 * pq, j1 = 2 * pq + 1;
        unsigned lo = ((n >> j0) & 1u) ? (0x3F80u | (((s >> j0) & 1u) << 15)) : 0u;
        unsigned hi = ((n >> j1) & 1u) ? (0x3F80u | (((s >> j1) & 1u) << 15)) : 0u;
        out[pq] = lo | (hi << 16);
      }
      uvec4 v = { out[0], out[1], out[2], out[3] };
      *(uvec4*)(wb + (long)w * 32 + q * 8) = v;
    }
  }
}

// ---- phase 2: bf16 GEMM, 256x256, BK=64, 8-wave, 8-phase, 32x32x16 MFMA -----
// v3 (R4 post-mortem): identical schedule/staging/vmcnt to v2; ONLY the MFMA
// shape changes 16x16x32 -> 32x32x16 (µbench 2382 vs 2075 TF: +15% FLOP/cyc on
// the matrix pipe, which is 51% of wall time). Per wave: 4 M-bands x 2 N-tiles
// of 32x32, K64 = 4 chained K16 steps per acc. Reads stay 12/4/4/4 b128/phase;
// swizzle slot = q ^ (row&7) with row&7 == lane&7 (bands 32-aligned) -> same
// 2-way-free bank behavior. Operand layout: lane l holds row/col l&31,
// k = (l>>5)*8 + j (K-contiguous 16 B, same pattern as the verified 16x16
// path). C/D: col = lane&31, row = (reg&3) + 8*(reg>>2) + 4*(lane>>5)
// (HW-verified m74/m101).
__global__ __launch_bounds__(512, 2) void gemm_kernel(const unsigned short* __restrict__ A,
                                                      const unsigned short* __restrict__ B,
                                                      const float* __restrict__ bias,
                                                      const float* __restrict__ alpha,
                                                      float* __restrict__ C) {
  __shared__ unsigned short lds[65536];   // 128 KiB: A [buf][half] then B

  const int tid  = threadIdx.x;
  const int lane = tid & 63;
  const int wave = tid >> 6;        // 8 waves: 2(M) x 4(N)
  const int wm   = wave >> 2;       // M offset wm*128
  const int wn   = wave & 3;        // N offset wn*64

  // XCD-aware bijective swizzle (nwg = 512, divisible by 8)
  const int wg   = blockIdx.x;
  const int swz  = (wg & 7) * 64 + (wg >> 3);
  const int nBlk = (swz & 15) * 256;
  const int mBlk = (swz >> 4) * 256;

  const unsigned short* Apan = A + (long)mBlk * K_DIM;
  const unsigned short* Bpan = B + (long)nBlk * K_DIM;

  // staging map (unchanged): half-tile = 128x64 bf16; dest linear (m104),
  // SOURCE carries the inverse swizzle (rule 21).
  int lOff[2], gOff[2];
#pragma unroll
  for (int l = 0; l < 2; ++l) {
    const int o = (l * 512 + tid) * 16;
    const int r = o >> 7;
    const int q = ((o >> 4) & 7) ^ (r & 7);
    lOff[l] = o;
    gOff[l] = r * K_DIM + q * 8;
  }

  // fragment addressing (32x32x16)
  const int rl = lane & 31;                       // row/col within 32-tile
  const int hi = lane >> 5;                       // k-group
  const int x7 = lane & 7;
  int qs[4];                                      // swizzled chunk slot per K16 g
#pragma unroll
  for (int g = 0; g < 4; ++g) qs[g] = (2 * g + hi) ^ x7;
  const int aRB = rl * 64;                        // row byte base (shorts)
  const int bNB = (wn & 1) * 4096 + rl * 64;      // B: 64-col group + row
  const int A0S = wm * 8192;                      // A buf0, half wm
  const int A1S = (2 + wm) * 8192;                // A buf1, half wm
  const int B0S = 32768 + (wn >> 1) * 8192;       // B buf0, half wn>>1
  const int B1S = 32768 + (2 + (wn >> 1)) * 8192; // B buf1, half wn>>1

  f32x16 acc[4][2] = {};                          // [m-band][n-tile] = 128 AGPR
  bf16x8 a[4], bv[2][4];                          // a: band x K16g; bv: ntile x K16g

#define STAGE(SUBv, BUFv, TILEv) do {                                          \
    const unsigned short* s_ = (((SUBv) < 2) ? Apan : Bpan)                    \
        + (long)((SUBv) & 1) * (128 * K_DIM) + (long)(TILEv) * 64;             \
    const int dB = ((((SUBv) < 2) ? 0 : 32768)                                 \
        + (((BUFv) * 2) + ((SUBv) & 1)) * 8192) * 2;                           \
    __builtin_amdgcn_global_load_lds(                                          \
        (const __attribute__((address_space(1))) void*)(s_ + gOff[0]),         \
        (__attribute__((address_space(3))) void*)((char*)lds + dB + lOff[0]),  \
        16, 0, 0);                                                             \
    __builtin_amdgcn_global_load_lds(                                          \
        (const __attribute__((address_space(1))) void*)(s_ + gOff[1]),         \
        (__attribute__((address_space(3))) void*)((char*)lds + dB + lOff[1]),  \
        16, 0, 0);                                                             \
  } while (0)

// A frags for M-band MB (rows MB*32..+31 of wave's half): 4 ds_read_b128
#define LOADA32(BASE, MB)                                                      \
  _Pragma("unroll")                                                            \
  for (int g = 0; g < 4; ++g)                                                  \
    a[g] = *(const bf16x8*)(lds + (BASE) + (MB) * 2048 + aRB + qs[g] * 8);

// all B frags of wave's 64-col group: 8 ds_read_b128 (only p1/p5)
#define LOADB32(BASE)                                                          \
  _Pragma("unroll")                                                            \
  for (int nt = 0; nt < 2; ++nt)                                               \
    _Pragma("unroll")                                                          \
    for (int g = 0; g < 4; ++g)                                                \
      bv[nt][g] = *(const bf16x8*)(lds + (BASE) + bNB + nt * 2048 + qs[g] * 8);

// 8 MFMA: band MB x 2 N-tiles x 4 chained K16 steps
#define MFMAPH(MB)                                                             \
  _Pragma("unroll")                                                            \
  for (int g = 0; g < 4; ++g)                                                  \
    _Pragma("unroll")                                                          \
    for (int nt = 0; nt < 2; ++nt)                                             \
      acc[MB][nt] = __builtin_amdgcn_mfma_f32_32x32x16_bf16(                   \
          a[g], bv[nt][g], acc[MB][nt], 0, 0, 0);

#define PRE12()   asm volatile("s_waitcnt lgkmcnt(8)" ::: "memory")
#define MID()  __builtin_amdgcn_s_barrier();                                   \
               asm volatile("s_waitcnt lgkmcnt(0)" ::: "memory");              \
               __builtin_amdgcn_s_setprio(1)
#define ENDPH()   __builtin_amdgcn_s_setprio(0); __builtin_amdgcn_s_barrier()
#define ENDVM4()  __builtin_amdgcn_s_setprio(0);                               \
                  asm volatile("s_waitcnt vmcnt(4)" ::: "memory");             \
                  __builtin_amdgcn_s_barrier()
#define ENDVM0()  __builtin_amdgcn_s_setprio(0);                               \
                  asm volatile("s_waitcnt vmcnt(0)" ::: "memory");             \
                  __builtin_amdgcn_s_barrier()

  // ---- prologue: tile0 {B0,B1,A0,A1} + tile1 {B0,B1} ----
  STAGE(2, 0, 0); STAGE(3, 0, 0); STAGE(0, 0, 0); STAGE(1, 0, 0);
  STAGE(2, 1, 1); STAGE(3, 1, 1);
  asm volatile("s_waitcnt vmcnt(4)" ::: "memory");   // tile 0 fully landed
  __builtin_amdgcn_s_barrier();

  // ---- main loop: 31 iterations, computing tiles 0..61 ----
  for (int it = 0; it < (K_DIM / 64) / 2 - 1; ++it) {
    const int t1 = 2 * it + 1, t2 = 2 * it + 2, t3 = 2 * it + 3;
    // p1..p4: tile 2it (buf0)
    LOADA32(A0S, 0); LOADB32(B0S); STAGE(1, 1, t1); PRE12();
                                                    MID(); MFMAPH(0); ENDPH();
    LOADA32(A0S, 1);               STAGE(0, 1, t1); MID(); MFMAPH(1); ENDPH();
    LOADA32(A0S, 2);               STAGE(2, 0, t2); MID(); MFMAPH(2); ENDPH();
    LOADA32(A0S, 3);               STAGE(3, 0, t2); MID(); MFMAPH(3); ENDVM4();
    // p5..p8: tile 2it+1 (buf1)
    LOADA32(A1S, 0); LOADB32(B1S); STAGE(0, 0, t2); PRE12();
                                                    MID(); MFMAPH(0); ENDPH();
    LOADA32(A1S, 1);               STAGE(1, 0, t2); MID(); MFMAPH(1); ENDPH();
    LOADA32(A1S, 2);               STAGE(2, 1, t3); MID(); MFMAPH(2); ENDPH();
    LOADA32(A1S, 3);               STAGE(3, 1, t3); MID(); MFMAPH(3); ENDVM4();
  }

  // ---- epilogue: tile 62 (buf0) + tile 63 (buf1) ----
  LOADA32(A0S, 0); LOADB32(B0S); STAGE(1, 1, 63); PRE12();
                                                  MID(); MFMAPH(0); ENDPH();
  LOADA32(A0S, 1);               STAGE(0, 1, 63); MID(); MFMAPH(1); ENDPH();
  LOADA32(A0S, 2);                                MID(); MFMAPH(2); ENDPH();
  LOADA32(A0S, 3);                                MID(); MFMAPH(3); ENDVM0();
  LOADA32(A1S, 0); LOADB32(B1S);                  MID(); MFMAPH(0); ENDPH();
  LOADA32(A1S, 1);                                MID(); MFMAPH(1); ENDPH();
  LOADA32(A1S, 2);                                MID(); MFMAPH(2); ENDPH();
  LOADA32(A1S, 3);                                MID(); MFMAPH(3);
  __builtin_amdgcn_s_setprio(0);

  // ---- C write: C[m][n] = acc * alpha[n] + bias[n] (nontemporal, write-once)
  // 32x32 C/D layout (verified m74/m101): col = lane&31,
  // row = (reg&3) + 8*(reg>>2) + 4*(lane>>5)
  const int nB0 = nBlk + wn * 64;
#pragma unroll
  for (int nt = 0; nt < 2; ++nt) {
    const int n = nB0 + nt * 32 + rl;
    const float al = alpha[n];
    const float bi = bias[n];
#pragma unroll
    for (int mb = 0; mb < 4; ++mb) {
      const int mBase = mBlk + wm * 128 + mb * 32 + 4 * hi;
#pragma unroll
      for (int r = 0; r < 16; ++r) {
        const int m = mBase + (r & 3) + 8 * (r >> 2);
        __builtin_nontemporal_store(acc[mb][nt][r] * al + bi,
                                    C + (long)m * O_DIM + n);
      }
    }
  }

#undef STAGE
#undef LOADA32
#undef LOADB32
#undef MFMAPH
#undef PRE12
#undef MID
#undef ENDPH
#undef ENDVM4
#undef ENDVM0
}

// ---- fallback (ws too small): slow but correct fp32 path --------------------
__global__ __launch_bounds__(256) void fallback_kernel(const float* __restrict__ x,
                                                       const unsigned* __restrict__ nz,
                                                       const unsigned* __restrict__ sgn,
                                                       const float* __restrict__ bias,
                                                       const float* __restrict__ alpha,
                                                       float* __restrict__ y) {
  long gid = (long)blockIdx.x * 256 + threadIdx.x;
  int o = (int)(gid % O_DIM);
  long m = gid / O_DIM;
  const float* xr = x + m * K_DIM;
  float s = 0.f;
  for (int w = 0; w < NWORDS; ++w) {
    unsigned n = nz[o * NWORDS + w];
    unsigned g = sgn[o * NWORDS + w];
    for (int j = 0; j < 32; ++j) {
      if ((n >> j) & 1u) {
        float v = xr[w * 32 + j];
        s += ((g >> j) & 1u) ? -v : v;
      }
    }
  }
  y[gid] = s * alpha[o] + bias[o];
}

extern "C" void kernel_launch(void* const* d_in, const int* in_sizes, int n_in,
                              void* d_out, int out_size, void* d_ws, size_t ws_size,
                              hipStream_t stream) {
  const float*    x     = (const float*)d_in[0];
  const unsigned* nz    = (const unsigned*)d_in[1];
  const unsigned* sgn   = (const unsigned*)d_in[2];
  const float*    bias  = (const float*)d_in[3];
  const float*    alpha = (const float*)d_in[4];
  float*          y     = (float*)d_out;

  const size_t xb_bytes = (size_t)M_DIM * K_DIM * 2;   // 64 MiB
  const size_t wb_bytes = (size_t)O_DIM * K_DIM * 2;   // 32 MiB

  if (ws_size >= xb_bytes + wb_bytes) {
    unsigned short* xb = (unsigned short*)d_ws;
    unsigned short* wb = (unsigned short*)((char*)d_ws + xb_bytes);

    prep_kernel<<<2560, 256, 0, stream>>>((const fvec4*)x, (uvec4*)xb, nz, sgn, wb);
    gemm_kernel<<<512, 512, 0, stream>>>(xb, wb, bias, alpha, y);
  } else {
    fallback_kernel<<<(long)M_DIM * O_DIM / 256, 256, 0, stream>>>(x, nz, sgn, bias, alpha, y);
  }
}